// Round 7
// baseline (82.744 us; speedup 1.0000x reference)
//
#include <hip/hip_runtime.h>

#define H 128
#define W 128
#define C 64
#define HW (H * W)
#define RAD 2
#define KD 5
#define KK 25

#define TSX 8
#define TSY 8
#define HROWS 12          // halo rows (y0-2 .. y0+9)
#define RSTR 24           // u32 per halo row (16 used; 24 -> sy bank spread {0,24,16,8})
#define PSTR 288          // HROWS * RSTR
#define GSTR 580          // 2*PSTR + 4: cs-group stride, bank phase 4*cs mod 32
#define LDSU (8 * GSTR)   // 4640 u32 = 18.56 KB -> 8 blocks/CU

#define SCALE_L2E 0.18033688011112042f  // (1/sqrt(64)) * log2(e)

typedef _Float16 h2 __attribute__((ext_vector_type(2)));

__device__ __forceinline__ float dot2acc(h2 a, h2 w, float acc)
{
#if __has_builtin(__builtin_amdgcn_fdot2)
    return __builtin_amdgcn_fdot2(a, w, acc, false);   // v_dot2_f32_f16
#else
    return fmaf((float)a.x, (float)w.x, fmaf((float)a.y, (float)w.y, acc));
#endif
}

__device__ __forceinline__ uint32_t pkh2(float lo, float hi)
{
    h2 t; t.x = (_Float16)lo; t.y = (_Float16)hi;
    return __builtin_bit_cast(uint32_t, t);
}
__device__ __forceinline__ h2 bch2(uint32_t u) { return __builtin_bit_cast(h2, u); }

// reduce across the 8 channel-groups: cs = lane bits 0..2.
// xor1/xor2 compile to DPP quad_perm (VALU pipe); xor4 to ds_swizzle.
__device__ __forceinline__ float cs_reduce(float x)
{
    x += __shfl_xor(x, 1, 64);
    x += __shfl_xor(x, 2, 64);
    x += __shfl_xor(x, 4, 64);
    return x;
}

template<bool MASKED>
__device__ __forceinline__ float2 softmax_eo(float (&cr)[KK], int xx, int yy)
{
    float m = -1e30f;
#pragma unroll
    for (int ky = 0; ky < KD; ++ky) {
#pragma unroll
        for (int kx = 0; kx < KD; ++kx) {
            int k = ky * KD + kx;
            float cv = cr[k] * SCALE_L2E;   // log2-domain
            if (MASKED) {
                int sxx = xx + kx - RAD, syy = yy + ky - RAD;
                bool valid = (sxx >= 0) && (sxx < W) && (syy >= 0) && (syy < H);
                cv = valid ? cv : -1e9f;
            }
            cr[k] = cv;
            m = fmaxf(m, cv);
        }
    }
    float sum = 0.f, ox = 0.f, oy = 0.f;
#pragma unroll
    for (int ky = 0; ky < KD; ++ky)
#pragma unroll
        for (int kx = 0; kx < KD; ++kx) {
            int k = ky * KD + kx;
            float e = exp2f(cr[k] - m);
            sum += e;
            ox += e * (float)(kx - RAD);
            oy += e * (float)(ky - RAD);
        }
    float inv = 1.f / sum;
    return make_float2(ox * inv, oy * inv);
}

__global__ __launch_bounds__(256, 7)
void bam_corr_softmax_kernel(const float* __restrict__ f0,
                             const float* __restrict__ f1,
                             const float* __restrict__ f2,
                             float* __restrict__ out)
{
    __shared__ uint32_t lds[LDSU];

    const int tid  = threadIdx.x;
    const int lane = tid & 63;
    const int wav  = tid >> 6;         // 0..3
    const int cs   = lane & 7;         // channel group 0..7 (4 pairs each)
    const int slot = lane >> 3;        // 0..7 pixel slot
    const int sx2  = slot & 3;
    const int syw  = slot >> 2;        // 0..1
    const int lx   = sx2 * 2;          // local x of first output (even)
    const int ly   = wav * 2 + syw;    // local y 0..7

    // XCD banding: band = blockIdx.x % 8 -> 16-row y-band per XCD L2 (~3.1MB);
    // consecutive blocks on an XCD cycle the 8 (v,b) jobs of the same tile.
    const int i     = blockIdx.x;
    const int band  = i & 7;
    const int j     = i >> 3;
    const int img   = j & 7;           // v*2 + b
    const int t     = j >> 3;          // 0..31
    const int tileX = t & 15;          // 0..15
    const int tileY = band * 2 + (t >> 4); // 0..15

    const int v = img >> 1;
    const int b = img & 1;

    const float* A;
    const float* Bf;
    if (v == 0)      { A = f0; Bf = f2; }
    else if (v == 1) { A = f1; Bf = f2; }
    else if (v == 2) { A = f2; Bf = f0; }
    else             { A = f2; Bf = f1; }

    const int x0 = tileX * TSX;
    const int y0 = tileY * TSY;
    const int x  = x0 + lx;
    const int y  = y0 + ly;

    const float* Arow  = A + (size_t)b * C * HW + (size_t)(y * W + x);
    const float* Bbase = Bf + (size_t)b * C * HW;

    const bool interior = (tileX >= 1) && (tileX <= 14) && (tileY >= 1) && (tileY <= 14);

    // ---- hoist ALL A-values to entry: no global latency in compute loop ----
    uint32_t a0c[4], a1c[4];
#pragma unroll
    for (int q = 0; q < 4; ++q) {
        int r = q >> 1, c = q & 1;
        int pair = r * 16 + cs * 2 + c;
        const float* ap = Arow + (size_t)(2 * pair) * HW;
        float2 alo = *reinterpret_cast<const float2*>(ap);       // ch 2*pair   @ x,x+1
        float2 ahi = *reinterpret_cast<const float2*>(ap + HW);  // ch 2*pair+1 @ x,x+1
        a0c[q] = pkh2(alo.x, ahi.x);
        a1c[q] = pkh2(alo.y, ahi.y);
    }

    float c0[KK], c1[KK];
#pragma unroll
    for (int k = 0; k < KK; ++k) { c0[k] = 0.f; c1[k] = 0.f; }

#pragma unroll
    for (int r = 0; r < 2; ++r) {
        if (r) __syncthreads();        // compute(r-1) done before LDS overwrite

        // ---- stage 16 pair-planes (12 rows x 16 u32) as uint4 chunks ----
        // 16 planes * 12 rows * 4 chunks = 768 = 3 per thread exactly
#pragma unroll
        for (int it = 0; it < 3; ++it) {
            int q   = tid + it * 256;
            int p   = q / 48;              // plane-in-round 0..15
            int rem = q - p * 48;
            int row = rem >> 2;
            int c4  = rem & 3;
            int gy  = y0 - 2 + row;
            int gx  = x0 - 4 + c4 * 4;
            int ch0 = 2 * (r * 16 + p);    // even channel of the pair
            float4 lo, hi;
            if (interior) {
                const float* p0 = Bbase + (size_t)ch0 * HW + (size_t)(gy * W + gx);
                lo = *reinterpret_cast<const float4*>(p0);
                hi = *reinterpret_cast<const float4*>(p0 + HW);
            } else {
                float lv[4], hv[4];
#pragma unroll
                for (int e = 0; e < 4; ++e) {
                    int gxe = gx + e;
                    bool ok = (gy >= 0) && (gy < H) && (gxe >= 0) && (gxe < W);
                    size_t off = (size_t)ch0 * HW + (size_t)(ok ? gy * W + gxe : 0);
                    lv[e] = ok ? Bbase[off] : 0.f;
                    hv[e] = ok ? Bbase[off + HW] : 0.f;
                }
                lo = make_float4(lv[0], lv[1], lv[2], lv[3]);
                hi = make_float4(hv[0], hv[1], hv[2], hv[3]);
            }
            uint4 wq = make_uint4(pkh2(lo.x, hi.x), pkh2(lo.y, hi.y),
                                  pkh2(lo.z, hi.z), pkh2(lo.w, hi.w));
            int g = p >> 1, c = p & 1;
            *reinterpret_cast<uint4*>(&lds[g * GSTR + c * PSTR + row * RSTR + c4 * 4]) = wq;
        }
        __syncthreads();

        // ---- compute: 2 pair-planes per cs-group this round ----
#pragma unroll
        for (int c = 0; c < 2; ++c) {
            h2 a0 = bch2(a0c[r * 2 + c]);
            h2 a1 = bch2(a1c[r * 2 + c]);
            // storage col lx+2 == global col x-2 (window start), 8B aligned
            const uint32_t* bp = &lds[cs * GSTR + c * PSTR + ly * RSTR + lx + 2];
#pragma unroll
            for (int rr = 0; rr < KD; ++rr) {
                const uint32_t* rp = bp + rr * RSTR;
                uint2 u01 = *reinterpret_cast<const uint2*>(rp);
                uint2 u23 = *reinterpret_cast<const uint2*>(rp + 2);
                uint2 u45 = *reinterpret_cast<const uint2*>(rp + 4);
                h2 w0 = bch2(u01.x), w1 = bch2(u01.y), w2 = bch2(u23.x);
                h2 w3 = bch2(u23.y), w4 = bch2(u45.x), w5 = bch2(u45.y);
                const int kb = rr * KD;
                c0[kb + 0] = dot2acc(a0, w0, c0[kb + 0]);
                c0[kb + 1] = dot2acc(a0, w1, c0[kb + 1]);
                c0[kb + 2] = dot2acc(a0, w2, c0[kb + 2]);
                c0[kb + 3] = dot2acc(a0, w3, c0[kb + 3]);
                c0[kb + 4] = dot2acc(a0, w4, c0[kb + 4]);
                c1[kb + 0] = dot2acc(a1, w1, c1[kb + 0]);
                c1[kb + 1] = dot2acc(a1, w2, c1[kb + 1]);
                c1[kb + 2] = dot2acc(a1, w3, c1[kb + 2]);
                c1[kb + 3] = dot2acc(a1, w4, c1[kb + 3]);
                c1[kb + 4] = dot2acc(a1, w5, c1[kb + 4]);
            }
        }
    }

    // ---- reduce the 8 channel-group partials ----
#pragma unroll
    for (int k = 0; k < KK; ++k) {
        c0[k] = cs_reduce(c0[k]);
        c1[k] = cs_reduce(c1[k]);
    }

    // ---- masked softmax + expected offset (mask only on border tiles) ----
    float2 r0, r1;
    if (interior) {
        r0 = softmax_eo<false>(c0, x,     y);
        r1 = softmax_eo<false>(c1, x + 1, y);
    } else {
        r0 = softmax_eo<true>(c0, x,     y);
        r1 = softmax_eo<true>(c1, x + 1, y);
    }

    if (cs == 0) {
        size_t ob = ((size_t)img * 2) * HW + (size_t)(y * W + x);
        *reinterpret_cast<float2*>(&out[ob])      = make_float2(r0.x, r1.x);
        *reinterpret_cast<float2*>(&out[ob + HW]) = make_float2(r0.y, r1.y);
    }
}

extern "C" void kernel_launch(void* const* d_in, const int* in_sizes, int n_in,
                              void* d_out, int out_size, void* d_ws, size_t ws_size,
                              hipStream_t stream)
{
    const float* f0 = (const float*)d_in[0];
    const float* f1 = (const float*)d_in[1];
    const float* f2 = (const float*)d_in[2];
    float* out = (float*)d_out;

    dim3 block(256, 1, 1);
    dim3 grid(2048, 1, 1); // 8 bands x 8 img x 32 tiles of 8x8
    bam_corr_softmax_kernel<<<grid, block, 0, stream>>>(f0, f1, f2, out);
}

// Round 10
// 27.955 us; speedup vs baseline: 2.9599x; 2.9599x over previous
//
#include <hip/hip_runtime.h>

#define H 128
#define W 128
#define C 64
#define HW (H * W)
#define RAD 2
#define KD 5
#define KK 25

#define TSX 16
#define TSY 8
#define HROWS 12          // halo rows (y0-2 .. y0+9)
#define RSTR 24           // u32 (channel-pairs) per halo row (x0-4 .. x0+19)
#define PSTR 292          // u32 per pair-plane: 12*24=288 +4 pad (16B-aligned)
#define NPAIR 32          // 64 channels as 32 pairs, all staged at once
#define LDSU (NPAIR * PSTR) // 9344 u32 = 36.5 KB -> 4 blocks/CU

#define SCALE_L2E 0.18033688011112042f  // (1/sqrt(64)) * log2(e)

typedef _Float16 h2 __attribute__((ext_vector_type(2)));
typedef __fp16 fp16v2 __attribute__((ext_vector_type(2)));

__device__ __forceinline__ float dot2acc(h2 a, h2 w, float acc)
{
#if __has_builtin(__builtin_amdgcn_fdot2)
    return __builtin_amdgcn_fdot2(a, w, acc, false);   // v_dot2_f32_f16
#else
    return fmaf((float)a.x, (float)w.x, fmaf((float)a.y, (float)w.y, acc));
#endif
}

// single-instruction f32x2 -> f16x2 pack (v_cvt_pkrtz_f16_f32)
__device__ __forceinline__ uint32_t pkh2(float lo, float hi)
{
#if __has_builtin(__builtin_amdgcn_cvt_pkrtz)
    fp16v2 t = __builtin_amdgcn_cvt_pkrtz(lo, hi);
    return __builtin_bit_cast(uint32_t, t);
#else
    h2 t; t.x = (_Float16)lo; t.y = (_Float16)hi;
    return __builtin_bit_cast(uint32_t, t);
#endif
}

__device__ __forceinline__ h2 bch2(uint32_t u) { return __builtin_bit_cast(h2, u); }

// cs-group reduction: cs = lane bits 4..5 -> xor16 + xor32 sums the 4 groups.
// SSA-safe HIP intrinsics (the inline-asm permlane swap version could have
// its two identical-valued operands coalesced into ONE register by the
// allocator, corrupting the swap -> R9's absmax 2.9 failure).
__device__ __forceinline__ float cs_reduce(float x)
{
    x += __shfl_xor(x, 16, 64);
    x += __shfl_xor(x, 32, 64);
    return x;
}

// exp2-domain softmax-expectation, no max-subtraction (|corr*scale| <= ~10,
// far inside f32 exp2 range; softmax is shift-invariant; masked taps -> 0).
template<bool MASKED>
__device__ __forceinline__ float2 softmax_eo(const float (&cr)[KK], int xx, int yy)
{
    float sum = 0.f, ox = 0.f, oy = 0.f;
#pragma unroll
    for (int ky = 0; ky < KD; ++ky) {
#pragma unroll
        for (int kx = 0; kx < KD; ++kx) {
            int k = ky * KD + kx;
            float e = exp2f(cr[k] * SCALE_L2E);
            if (MASKED) {
                int sxx = xx + kx - RAD, syy = yy + ky - RAD;
                bool valid = (sxx >= 0) && (sxx < W) && (syy >= 0) && (syy < H);
                e = valid ? e : 0.f;
            }
            sum += e;
            ox += e * (float)(kx - RAD);
            oy += e * (float)(ky - RAD);
        }
    }
    float inv = 1.f / sum;
    return make_float2(ox * inv, oy * inv);
}

__global__ __launch_bounds__(256, 4)
void bam_corr_softmax_kernel(const float* __restrict__ f0,
                             const float* __restrict__ f1,
                             const float* __restrict__ f2,
                             float* __restrict__ out)
{
    __shared__ uint32_t lds[LDSU];

    const int tid  = threadIdx.x;
    const int lane = tid & 63;
    const int wav  = tid >> 6;
    const int cs   = lane >> 4;        // channel group 0..3 (8 pairs each)
    const int s    = lane & 15;
    const int sy   = s >> 2;           // 0..3
    const int sxp  = s & 3;            // 0..3
    const int wx   = wav & 1;
    const int wy   = wav >> 1;
    const int lx   = wx * 8 + sxp * 2; // local x of first output (even)
    const int ly   = wy * 4 + sy;      // local y

    // XCD banding: band = blockIdx.x % 8 -> 16-row y-band per XCD L2 (~3.1MB).
    const int i     = blockIdx.x;
    const int band  = i & 7;
    const int j     = i >> 3;
    const int img   = j & 7;           // v*2 + b
    const int t     = j >> 3;          // 0..15
    const int tileX = t & 7;           // 0..7
    const int tileY = band * 2 + (t >> 3); // 0..15

    const int v = img >> 1;
    const int b = img & 1;

    const float* A;
    const float* Bf;
    if (v == 0)      { A = f0; Bf = f2; }
    else if (v == 1) { A = f1; Bf = f2; }
    else if (v == 2) { A = f2; Bf = f0; }
    else             { A = f2; Bf = f1; }

    const int x0 = tileX * TSX;
    const int y0 = tileY * TSY;
    const int x  = x0 + lx;
    const int y  = y0 + ly;

    const float* Arow  = A + (size_t)b * C * HW + (size_t)(y * W + x);
    const float* Bbase = Bf + (size_t)b * C * HW;

    const bool interior = (tileX >= 1) && (tileX <= 6) && (tileY >= 1) && (tileY <= 14);

    // ---- hoist ALL A-values to entry: latency overlaps staging loads,
    //      compute loop is pure LDS + dot2 ----
    uint32_t a0c[8], a1c[8];
#pragma unroll
    for (int c = 0; c < 8; ++c) {
        const int pl = cs * 8 + c;
        const float* ap = Arow + (size_t)(2 * pl) * HW;
        float2 alo = *reinterpret_cast<const float2*>(ap);       // ch 2pl   @ x,x+1
        float2 ahi = *reinterpret_cast<const float2*>(ap + HW);  // ch 2pl+1 @ x,x+1
        a0c[c] = pkh2(alo.x, ahi.x);
        a1c[c] = pkh2(alo.y, ahi.y);
    }

    // ---- stage ALL 64 channels as 32 f16 pair-planes (12x24 halo) ----
    // 32 planes * 12 rows * 6 chunks = 2304 = 9 per thread exactly
#pragma unroll
    for (int it = 0; it < 9; ++it) {
        int q   = tid + it * 256;
        int p   = q / 72;              // pair-plane 0..31
        int rem = q - p * 72;
        int row = rem / 6;
        int c6  = rem - row * 6;
        int gy  = y0 - 2 + row;
        int gx  = x0 - 4 + c6 * 4;
        float4 lo, hi;
        if (interior) {
            const float* p0 = Bbase + (size_t)(2 * p) * HW + (size_t)(gy * W + gx);
            lo = *reinterpret_cast<const float4*>(p0);
            hi = *reinterpret_cast<const float4*>(p0 + HW);
        } else {
            float lv[4], hv[4];
#pragma unroll
            for (int e = 0; e < 4; ++e) {
                int gxe = gx + e;
                bool ok = (gy >= 0) && (gy < H) && (gxe >= 0) && (gxe < W);
                size_t off = (size_t)(2 * p) * HW + (size_t)(ok ? gy * W + gxe : 0);
                lv[e] = ok ? Bbase[off] : 0.f;
                hv[e] = ok ? Bbase[off + HW] : 0.f;
            }
            lo = make_float4(lv[0], lv[1], lv[2], lv[3]);
            hi = make_float4(hv[0], hv[1], hv[2], hv[3]);
        }
        uint4 wq = make_uint4(pkh2(lo.x, hi.x), pkh2(lo.y, hi.y),
                              pkh2(lo.z, hi.z), pkh2(lo.w, hi.w));
        *reinterpret_cast<uint4*>(&lds[p * PSTR + row * RSTR + c6 * 4]) = wq;
    }
    __syncthreads();   // the ONLY barrier

    // ---- compute: 8 channel-pairs per cs-group, 2 x-outputs per thread ----
    float c0[KK], c1[KK];
#pragma unroll
    for (int k = 0; k < KK; ++k) { c0[k] = 0.f; c1[k] = 0.f; }

#pragma unroll
    for (int c = 0; c < 8; ++c) {
        const int pl = cs * 8 + c;
        h2 a0 = bch2(a0c[c]);
        h2 a1 = bch2(a1c[c]);
        // storage col (lx+2) == global col x-2 (window start), 8B aligned
        const uint32_t* bp = &lds[pl * PSTR + ly * RSTR + lx + 2];
#pragma unroll
        for (int rr = 0; rr < KD; ++rr) {
            const uint32_t* rp = bp + rr * RSTR;
            uint2 u01 = *reinterpret_cast<const uint2*>(rp);
            uint2 u23 = *reinterpret_cast<const uint2*>(rp + 2);
            uint2 u45 = *reinterpret_cast<const uint2*>(rp + 4);
            h2 w0 = bch2(u01.x), w1 = bch2(u01.y), w2 = bch2(u23.x);
            h2 w3 = bch2(u23.y), w4 = bch2(u45.x), w5 = bch2(u45.y);
            const int kb = rr * KD;
            c0[kb + 0] = dot2acc(a0, w0, c0[kb + 0]);
            c0[kb + 1] = dot2acc(a0, w1, c0[kb + 1]);
            c0[kb + 2] = dot2acc(a0, w2, c0[kb + 2]);
            c0[kb + 3] = dot2acc(a0, w3, c0[kb + 3]);
            c0[kb + 4] = dot2acc(a0, w4, c0[kb + 4]);
            c1[kb + 0] = dot2acc(a1, w1, c1[kb + 0]);
            c1[kb + 1] = dot2acc(a1, w2, c1[kb + 1]);
            c1[kb + 2] = dot2acc(a1, w3, c1[kb + 2]);
            c1[kb + 3] = dot2acc(a1, w4, c1[kb + 3]);
            c1[kb + 4] = dot2acc(a1, w5, c1[kb + 4]);
        }
    }

    // ---- reduce the 4 channel-group partials ----
#pragma unroll
    for (int k = 0; k < KK; ++k) {
        c0[k] = cs_reduce(c0[k]);
        c1[k] = cs_reduce(c1[k]);
    }

    // ---- softmax + expected offset (mask only on border tiles) ----
    float2 r0, r1;
    if (interior) {
        r0 = softmax_eo<false>(c0, x,     y);
        r1 = softmax_eo<false>(c1, x + 1, y);
    } else {
        r0 = softmax_eo<true>(c0, x,     y);
        r1 = softmax_eo<true>(c1, x + 1, y);
    }

    if (cs == 0) {
        size_t ob = ((size_t)img * 2) * HW + (size_t)(y * W + x);
        *reinterpret_cast<float2*>(&out[ob])      = make_float2(r0.x, r1.x);
        *reinterpret_cast<float2*>(&out[ob + HW]) = make_float2(r0.y, r1.y);
    }
}

extern "C" void kernel_launch(void* const* d_in, const int* in_sizes, int n_in,
                              void* d_out, int out_size, void* d_ws, size_t ws_size,
                              hipStream_t stream)
{
    const float* f0 = (const float*)d_in[0];
    const float* f1 = (const float*)d_in[1];
    const float* f2 = (const float*)d_in[2];
    float* out = (float*)d_out;

    dim3 block(256, 1, 1);
    dim3 grid(1024, 1, 1); // 8 bands x 8 img x 16 tiles of 16x8
    bam_corr_softmax_kernel<<<grid, block, 0, stream>>>(f0, f1, f2, out);
}